// Round 1
// baseline (625.685 us; speedup 1.0000x reference)
//
#include <hip/hip_runtime.h>
#include <math.h>

#define N_NODES 100000
#define N_EDGES 1600000
#define DOUT_   64
#define EPS_    1e-5f

// ---------------------------------------------------------------------------
// Kernel 1: h = relu(x @ W1 + b1)  [N,64]  -> written to d_out[:, :64]
//           hg = h @ Wg            [N,64]  -> workspace
// One wave per node; lane = output channel. Wg (16 KB) staged in LDS.
// ---------------------------------------------------------------------------
__global__ void lin_kernel(const float* __restrict__ x,
                           const float* __restrict__ W1,
                           const float* __restrict__ b1,
                           const float* __restrict__ Wg,
                           float* __restrict__ out,   // [N,128], h -> cols 0..63
                           float* __restrict__ hg)    // [N,64]
{
    __shared__ float sWg[64 * 64];
    for (int i = threadIdx.x; i < 64 * 64; i += blockDim.x) sWg[i] = Wg[i];
    __syncthreads();

    const int lane   = threadIdx.x & 63;
    const int wave   = blockIdx.x * (blockDim.x >> 6) + (threadIdx.x >> 6);
    const int nwaves = gridDim.x * (blockDim.x >> 6);

    for (int n = wave; n < N_NODES; n += nwaves) {
        const float x0 = x[n * 3 + 0];
        const float x1 = x[n * 3 + 1];
        const float x2 = x[n * 3 + 2];
        float h = x0 * W1[lane] + x1 * W1[64 + lane] + x2 * W1[128 + lane] + b1[lane];
        h = fmaxf(h, 0.0f);

        float acc = 0.0f;
#pragma unroll 16
        for (int k = 0; k < 64; ++k) {
            const float hk = __shfl(h, k, 64);        // broadcast h_k across wave
            acc = fmaf(hk, sWg[k * 64 + lane], acc);  // lane c: Wg[k][c], conflict-free
        }
        out[n * 128 + lane] = h;
        hg[n * 64 + lane]   = acc;
    }
}

// ---------------------------------------------------------------------------
// Kernel 2: deg[dst] += 1 over edges (self-loop's +1 folded in later)
// ---------------------------------------------------------------------------
__global__ void deg_kernel(const int* __restrict__ dst, int* __restrict__ deg)
{
    const int e = blockIdx.x * blockDim.x + threadIdx.x;
    if (e < N_EDGES) atomicAdd(&deg[dst[e]], 1);
}

// ---------------------------------------------------------------------------
// Kernel 3: dinv[n] = rsqrt(deg[n] + 1)   (+1 = self loop; always > 0)
// ---------------------------------------------------------------------------
__global__ void dinv_kernel(const int* __restrict__ deg, float* __restrict__ dinv)
{
    const int n = blockIdx.x * blockDim.x + threadIdx.x;
    if (n < N_NODES) dinv[n] = rsqrtf((float)(deg[n] + 1));
}

// ---------------------------------------------------------------------------
// Kernel 4: scatter-add  agg[dst] += hg[src] * dinv[src]*dinv[dst]
// One wave per edge, lane = channel. Reads of hg[src*64+c] coalesced (256 B).
// ---------------------------------------------------------------------------
__global__ void scatter_kernel(const int* __restrict__ src,
                               const int* __restrict__ dst,
                               const float* __restrict__ dinv,
                               const float* __restrict__ hg,
                               float* __restrict__ agg)
{
    const long long tid = (long long)blockIdx.x * blockDim.x + threadIdx.x;
    const int e = (int)(tid >> 6);
    const int c = (int)(tid & 63);
    if (e >= N_EDGES) return;
    const int s = src[e];
    const int d = dst[e];
    const float w = dinv[s] * dinv[d];
    atomicAdd(&agg[d * 64 + c], hg[s * 64 + c] * w);
}

// ---------------------------------------------------------------------------
// Kernel 5: h2 = relu(agg + hg*dinv^2 (self loop) + bg); cat=[h,h2];
//           LayerNorm(128) with gamma/beta. One wave per node; lane holds
//           channels c and c+64. Shuffle-reduce for mean/var.
// ---------------------------------------------------------------------------
__global__ void final_kernel(const float* __restrict__ hg,
                             const float* __restrict__ agg,
                             const float* __restrict__ dinv,
                             const float* __restrict__ bg,
                             const float* __restrict__ gamma,
                             const float* __restrict__ beta,
                             float* __restrict__ out)   // [N,128]; cols 0..63 hold h
{
    const int lane = threadIdx.x & 63;
    const int n    = blockIdx.x * (blockDim.x >> 6) + (threadIdx.x >> 6);
    if (n >= N_NODES) return;

    const float h  = out[n * 128 + lane];
    const float di = dinv[n];
    float h2 = agg[n * 64 + lane] + hg[n * 64 + lane] * di * di + bg[lane];
    h2 = fmaxf(h2, 0.0f);

    float sum = h + h2;
#pragma unroll
    for (int o = 32; o > 0; o >>= 1) sum += __shfl_xor(sum, o, 64);
    const float mu = sum * (1.0f / 128.0f);

    const float d0 = h - mu;
    const float d1 = h2 - mu;
    float vs = d0 * d0 + d1 * d1;
#pragma unroll
    for (int o = 32; o > 0; o >>= 1) vs += __shfl_xor(vs, o, 64);
    const float r = rsqrtf(vs * (1.0f / 128.0f) + EPS_);

    out[n * 128 + lane]      = d0 * r * gamma[lane]      + beta[lane];
    out[n * 128 + 64 + lane] = d1 * r * gamma[64 + lane] + beta[64 + lane];
}

// ---------------------------------------------------------------------------
extern "C" void kernel_launch(void* const* d_in, const int* in_sizes, int n_in,
                              void* d_out, int out_size, void* d_ws, size_t ws_size,
                              hipStream_t stream)
{
    const float* x     = (const float*)d_in[0];
    const int*   edge  = (const int*)  d_in[1];   // [2, E]: row0 = src, row1 = dst
    const float* W1    = (const float*)d_in[2];
    const float* b1    = (const float*)d_in[3];
    const float* Wg    = (const float*)d_in[4];
    const float* bg    = (const float*)d_in[5];
    const float* gamma = (const float*)d_in[6];
    const float* beta  = (const float*)d_in[7];
    float*       out   = (float*)d_out;

    // Workspace layout (~52 MB): hg | agg | deg | dinv
    char*  ws   = (char*)d_ws;
    float* hg   = (float*)ws;
    float* agg  = (float*)(ws + (size_t)N_NODES * 64 * sizeof(float));
    int*   deg  = (int*)  (ws + 2 * (size_t)N_NODES * 64 * sizeof(float));
    float* dinv = (float*)(ws + 2 * (size_t)N_NODES * 64 * sizeof(float)
                              + (size_t)N_NODES * sizeof(int));

    const int* src = edge;
    const int* dst = edge + N_EDGES;

    hipMemsetAsync(agg, 0, (size_t)N_NODES * 64 * sizeof(float), stream);
    hipMemsetAsync(deg, 0, (size_t)N_NODES * sizeof(int), stream);

    lin_kernel<<<1024, 256, 0, stream>>>(x, W1, b1, Wg, out, hg);
    deg_kernel<<<(N_EDGES + 255) / 256, 256, 0, stream>>>(dst, deg);
    dinv_kernel<<<(N_NODES + 255) / 256, 256, 0, stream>>>(deg, dinv);

    const long long scatter_threads = (long long)N_EDGES * 64;
    scatter_kernel<<<(int)(scatter_threads / 256), 256, 0, stream>>>(src, dst, dinv, hg, agg);

    final_kernel<<<(N_NODES + 3) / 4, 256, 0, stream>>>(hg, agg, dinv, bg, gamma, beta, out);
}